// Round 1
// baseline (2071.019 us; speedup 1.0000x reference)
//
#include <hip/hip_runtime.h>
#include <math.h>

#define B_ 2
#define C_ 192
#define C2_ 384
#define H_ 128
#define W_ 128
#define N_ (H_*W_)      // 16384
#define HEADS_ 4
#define HD_ 48
#define NS_ 16
#define EPS_ 1e-12f

// ---------------- K0: transpose reg_w [oc][c][t] -> regwT [t][c][oc] ----------------
__global__ __launch_bounds__(256) void k_regw_t(const float* __restrict__ regw, float* __restrict__ regwT) {
    int idx = blockIdx.x * 256 + threadIdx.x;
    const int total = 9 * C2_ * C2_;
    if (idx >= total) return;
    int t = idx / (C2_ * C2_);
    int r = idx - t * (C2_ * C2_);
    int c = r / C2_;
    int oc = r - c * C2_;
    regwT[idx] = regw[(oc * C2_ + c) * 9 + t];
}

// ---------------- K1: kv 1x1 conv, output pixel-major kvT[b][p][oc] ----------------
__global__ __launch_bounds__(256) void k_kv1x1(const float* __restrict__ x, const float* __restrict__ kvw,
                                               float* __restrict__ kvT) {
    __shared__ float Xs[16][68];
    __shared__ float Ws[16][68];
    const int b   = blockIdx.z;
    const int p0  = blockIdx.x * 64;
    const int oc0 = blockIdx.y * 64;
    const int tid = threadIdx.x;
    const int tp  = tid >> 4;   // pixel sub-tile
    const int to  = tid & 15;   // oc sub-tile
    float acc[4][4] = {};
    for (int k0 = 0; k0 < C_; k0 += 16) {
        for (int e = tid; e < 1024; e += 256) {
            int k = e >> 6, p = e & 63;
            Xs[k][p] = x[((size_t)b * C_ + k0 + k) * N_ + p0 + p];
            int oc = e >> 4, kk = e & 15;
            Ws[kk][oc] = kvw[(oc0 + oc) * C_ + k0 + kk];
        }
        __syncthreads();
        #pragma unroll
        for (int k = 0; k < 16; ++k) {
            float4 a = *(const float4*)&Xs[k][tp * 4];
            float4 w = *(const float4*)&Ws[k][to * 4];
            float av[4] = {a.x, a.y, a.z, a.w};
            float wv[4] = {w.x, w.y, w.z, w.w};
            #pragma unroll
            for (int i = 0; i < 4; ++i)
                #pragma unroll
                for (int j = 0; j < 4; ++j) acc[i][j] += av[i] * wv[j];
        }
        __syncthreads();
    }
    #pragma unroll
    for (int i = 0; i < 4; ++i) {
        int p = p0 + tp * 4 + i;
        float4 st = make_float4(acc[i][0], acc[i][1], acc[i][2], acc[i][3]);
        *(float4*)&kvT[((size_t)b * N_ + p) * C2_ + oc0 + to * 4] = st;
    }
}

// ---------------- K2: normalize q rows over n, write to output qh region ----------------
__global__ __launch_bounds__(256) void k_qnorm(const float* __restrict__ q, float* __restrict__ qn) {
    const int row = blockIdx.x;       // b*C + c
    const float* src = q + (size_t)row * N_;
    float* dst = qn + (size_t)row * N_;
    float ss = 0.f;
    for (int i = threadIdx.x; i < N_ / 4; i += 256) {
        float4 v = ((const float4*)src)[i];
        ss += v.x * v.x + v.y * v.y + v.z * v.z + v.w * v.w;
    }
    __shared__ float red[256];
    red[threadIdx.x] = ss;
    __syncthreads();
    for (int s = 128; s > 0; s >>= 1) {
        if (threadIdx.x < s) red[threadIdx.x] += red[threadIdx.x + s];
        __syncthreads();
    }
    float rn = 1.f / fmaxf(sqrtf(red[0]), EPS_);
    for (int i = threadIdx.x; i < N_ / 4; i += 256) {
        float4 v = ((const float4*)src)[i];
        ((float4*)dst)[i] = make_float4(v.x * rn, v.y * rn, v.z * rn, v.w * rn);
    }
}

// ---------------- K5: 1/||k row|| for k rows of kvd ----------------
__global__ __launch_bounds__(256) void k_knorm(const float* __restrict__ kvd, float* __restrict__ knorm) {
    const int b = blockIdx.x / C_;
    const int c = blockIdx.x % C_;
    const float* src = kvd + ((size_t)b * C2_ + c) * N_;
    float ss = 0.f;
    for (int i = threadIdx.x; i < N_ / 4; i += 256) {
        float4 v = ((const float4*)src)[i];
        ss += v.x * v.x + v.y * v.y + v.z * v.z + v.w * v.w;
    }
    __shared__ float red[256];
    red[threadIdx.x] = ss;
    __syncthreads();
    for (int s = 128; s > 0; s >>= 1) {
        if (threadIdx.x < s) red[threadIdx.x] += red[threadIdx.x + s];
        __syncthreads();
    }
    if (threadIdx.x == 0) knorm[blockIdx.x] = 1.f / fmaxf(sqrtf(red[0]), EPS_);
}

// ---------------- K3: offset conv3x3 (18 out ch), one wave per 8 pixels ----------------
__global__ __launch_bounds__(256) void k_offconv(const float* __restrict__ kvT, const float* __restrict__ offw,
                                                 const float* __restrict__ offb, float* __restrict__ offT) {
    const int b    = blockIdx.y;
    const int wv   = threadIdx.x >> 6;
    const int lane = threadIdx.x & 63;
    const int p0   = (blockIdx.x * 4 + wv) * 8;   // 8 consecutive pixels, same row
    const int y    = p0 >> 7;
    const int x0   = p0 & 127;
    const float* base = kvT + (size_t)b * N_ * C2_;
    #pragma unroll
    for (int half = 0; half < 2; ++half) {
        float acc[9][8];
        #pragma unroll
        for (int o = 0; o < 9; ++o)
            #pragma unroll
            for (int px = 0; px < 8; ++px) acc[o][px] = 0.f;
        for (int i = 0; i < 6; ++i) {
            const int c = i * 64 + lane;
            float vals[9][8];
            #pragma unroll
            for (int t = 0; t < 9; ++t) {
                const int dy = t / 3 - 1, dx = t % 3 - 1;
                const bool vy = (unsigned)(y + dy) < H_;
                #pragma unroll
                for (int px = 0; px < 8; ++px) {
                    const bool v = vy && ((unsigned)(x0 + px + dx) < W_);
                    const int qp = v ? (p0 + px + dy * W_ + dx) : 0;
                    float val = base[(size_t)qp * C2_ + c];
                    vals[t][px] = v ? val : 0.f;
                }
            }
            #pragma unroll
            for (int o = 0; o < 9; ++o) {
                const float* wp = offw + ((size_t)(half * 9 + o) * C2_ + c) * 9;
                float w9[9];
                #pragma unroll
                for (int t = 0; t < 9; ++t) w9[t] = wp[t];
                #pragma unroll
                for (int t = 0; t < 9; ++t)
                    #pragma unroll
                    for (int px = 0; px < 8; ++px) acc[o][px] += vals[t][px] * w9[t];
            }
        }
        // reduce over 64 lanes (channel split)
        #pragma unroll
        for (int o = 0; o < 9; ++o)
            #pragma unroll
            for (int px = 0; px < 8; ++px)
                #pragma unroll
                for (int m = 32; m > 0; m >>= 1)
                    acc[o][px] += __shfl_xor(acc[o][px], m);
        if (lane == 0) {
            #pragma unroll
            for (int px = 0; px < 8; ++px)
                #pragma unroll
                for (int o = 0; o < 9; ++o)
                    offT[((size_t)b * N_ + p0 + px) * 18 + half * 9 + o] = acc[o][px] + offb[half * 9 + o];
        }
    }
}

// ---------------- K4: deformable conv3x3 -> kvd[b][oc][p] (channel-major) ----------------
__global__ __launch_bounds__(256) void k_deform(const float* __restrict__ kvT, const float* __restrict__ offT,
                                                const float* __restrict__ regwT, float* __restrict__ kvd) {
    __shared__ float As[16][36];
    __shared__ float Ws[16][388];
    __shared__ float wwt[32][4];
    __shared__ int   widx[32][4];
    const int b  = blockIdx.y;
    const int p0 = blockIdx.x * 32;
    const int tid = threadIdx.x;
    const int to = tid & 31;   // oc group: 12 oc each
    const int tp = tid >> 5;   // pixel group: 4 px each
    const int sp = tid >> 3;   // staging: pixel 0..31
    const int sk = (tid & 7) * 2;  // staging: k pair
    float acc[4][12] = {};
    const float* kbase = kvT + (size_t)b * N_ * C2_;
    for (int t = 0; t < 9; ++t) {
        if (tid < 32) {
            const int p = p0 + tid;
            const int yy = p >> 7, xx = p & 127;
            const float dy = offT[((size_t)b * N_ + p) * 18 + 2 * t];
            const float dx = offT[((size_t)b * N_ + p) * 18 + 2 * t + 1];
            const float py = (float)(yy + t / 3 - 1) + dy;
            const float px = (float)(xx + t % 3 - 1) + dx;
            const float fy = floorf(py), fx = floorf(px);
            const int y0 = (int)fy, x0i = (int)fx;
            const float ay = py - fy, ax = px - fx;
            #pragma unroll
            for (int j = 0; j < 4; ++j) {
                const int yi = y0 + (j >> 1);
                const int xi = x0i + (j & 1);
                const float wj = ((j >> 1) ? ay : 1.f - ay) * ((j & 1) ? ax : 1.f - ax);
                const bool v = ((unsigned)yi < H_) && ((unsigned)xi < W_);
                wwt[tid][j]  = v ? wj : 0.f;
                widx[tid][j] = v ? (yi * W_ + xi) : 0;
            }
        }
        __syncthreads();
        for (int cc = 0; cc < C2_; cc += 16) {
            // stage weights for this tap/chunk (coalesced: oc contiguous)
            const float* wbase = regwT + ((size_t)t * C2_ + cc) * C2_;
            for (int e = tid; e < 16 * C2_; e += 256) {
                int k = e / C2_;
                int oc = e - k * C2_;
                Ws[k][oc] = wbase[(size_t)k * C2_ + oc];
            }
            // stage sampled A tile: As[k][p] = bilinear(kvT)[p][cc+k]
            {
                float s0 = 0.f, s1 = 0.f;
                const float* cb = kbase + cc + sk;
                #pragma unroll
                for (int j = 0; j < 4; ++j) {
                    const float wj = wwt[sp][j];
                    const float* cp = cb + (size_t)widx[sp][j] * C2_;
                    s0 += wj * cp[0];
                    s1 += wj * cp[1];
                }
                As[sk][sp]     = s0;
                As[sk + 1][sp] = s1;
            }
            __syncthreads();
            #pragma unroll
            for (int k = 0; k < 16; ++k) {
                float4 a = *(const float4*)&As[k][tp * 4];
                float av[4] = {a.x, a.y, a.z, a.w};
                float wv[12];
                #pragma unroll
                for (int m = 0; m < 3; ++m) {
                    float4 w = *(const float4*)&Ws[k][to * 12 + m * 4];
                    wv[m * 4 + 0] = w.x; wv[m * 4 + 1] = w.y; wv[m * 4 + 2] = w.z; wv[m * 4 + 3] = w.w;
                }
                #pragma unroll
                for (int i = 0; i < 4; ++i)
                    #pragma unroll
                    for (int j = 0; j < 12; ++j) acc[i][j] += av[i] * wv[j];
            }
            __syncthreads();
        }
    }
    #pragma unroll
    for (int j = 0; j < 12; ++j) {
        const int oc = to * 12 + j;
        float4 st = make_float4(acc[0][j], acc[1][j], acc[2][j], acc[3][j]);
        *(float4*)&kvd[((size_t)b * C2_ + oc) * N_ + p0 + tp * 4] = st;
    }
}

// ---------------- K6a: attention logits partial GEMM (48x48 per (b,h), split over n) ----------------
__global__ __launch_bounds__(256) void k_attn_partial(const float* __restrict__ qn, const float* __restrict__ kvd,
                                                      float* __restrict__ part) {
    __shared__ float Qs[64][49];
    __shared__ float Ks[64][49];
    const int sl = blockIdx.x;
    const int h  = blockIdx.y;
    const int b  = blockIdx.z;
    const int tid = threadIdx.x;
    const int td = tid >> 4, te = tid & 15;
    const int n0 = sl * (N_ / NS_);
    float acc[3][3] = {};
    for (int nc = 0; nc < N_ / NS_; nc += 64) {
        for (int e = tid; e < HD_ * 64; e += 256) {
            int d = e >> 6, kk = e & 63;
            Qs[kk][d] = qn[((size_t)b * C_ + h * HD_ + d) * N_ + n0 + nc + kk];
            Ks[kk][d] = kvd[((size_t)b * C2_ + h * HD_ + d) * N_ + n0 + nc + kk];
        }
        __syncthreads();
        #pragma unroll 8
        for (int kk = 0; kk < 64; ++kk) {
            float a[3], bb[3];
            #pragma unroll
            for (int i = 0; i < 3; ++i) a[i] = Qs[kk][td * 3 + i];
            #pragma unroll
            for (int j = 0; j < 3; ++j) bb[j] = Ks[kk][te * 3 + j];
            #pragma unroll
            for (int i = 0; i < 3; ++i)
                #pragma unroll
                for (int j = 0; j < 3; ++j) acc[i][j] += a[i] * bb[j];
        }
        __syncthreads();
    }
    float* pp = part + ((((size_t)b * HEADS_ + h) * NS_ + sl) * HD_) * HD_;
    #pragma unroll
    for (int i = 0; i < 3; ++i)
        #pragma unroll
        for (int j = 0; j < 3; ++j)
            pp[(td * 3 + i) * HD_ + te * 3 + j] = acc[i][j];
}

// ---------------- K6b: reduce partials, scale by knorm & temperature, softmax over e ----------------
__global__ __launch_bounds__(64) void k_softmax(const float* __restrict__ part, const float* __restrict__ knorm,
                                                const float* __restrict__ temp, float* __restrict__ attn) {
    const int row = blockIdx.x;    // b*HEADS*HD + h*HD + d
    const int b = row / (HEADS_ * HD_);
    const int r = row % (HEADS_ * HD_);
    const int h = r / HD_;
    const int d = r % HD_;
    const int e = threadIdx.x;
    float v = -INFINITY;
    if (e < HD_) {
        float s = 0.f;
        for (int sl = 0; sl < NS_; ++sl)
            s += part[((((size_t)b * HEADS_ + h) * NS_ + sl) * HD_ + d) * HD_ + e];
        v = s * knorm[b * C_ + h * HD_ + e] * temp[h];
    }
    float m = v;
    #pragma unroll
    for (int off = 32; off > 0; off >>= 1) m = fmaxf(m, __shfl_xor(m, off));
    float ex = (e < HD_) ? expf(v - m) : 0.f;
    float sum = ex;
    #pragma unroll
    for (int off = 32; off > 0; off >>= 1) sum += __shfl_xor(sum, off);
    if (e < HD_)
        attn[(((size_t)b * HEADS_ + h) * HD_ + d) * HD_ + e] = ex / sum;
}

// ---------------- K7: fuse proj_w with attn: M[b][oc][h*48+e] ----------------
__global__ __launch_bounds__(256) void k_m(const float* __restrict__ projw, const float* __restrict__ attn,
                                           float* __restrict__ Mm) {
    const int gid = blockIdx.x * 256 + threadIdx.x;
    if (gid >= B_ * C_ * C_) return;
    const int b  = gid / (C_ * C_);
    const int r  = gid % (C_ * C_);
    const int oc = r / C_;
    const int he = r % C_;
    const int h = he / HD_;
    const int e = he % HD_;
    float s = 0.f;
    #pragma unroll 8
    for (int d = 0; d < HD_; ++d)
        s += projw[oc * C_ + h * HD_ + d] * attn[(((size_t)b * HEADS_ + h) * HD_ + d) * HD_ + e];
    Mm[gid] = s;
}

// ---------------- K8: out[b][oc][p] = sum_he M[b][oc][he] * v[b][he][p] ----------------
__global__ __launch_bounds__(256) void k_out(const float* __restrict__ Mm, const float* __restrict__ kvd,
                                             float* __restrict__ out) {
    __shared__ float Vs[16][68];
    __shared__ float Ms[16][68];
    const int b   = blockIdx.z;
    const int p0  = blockIdx.x * 64;
    const int oc0 = blockIdx.y * 64;
    const int tid = threadIdx.x;
    const int tp  = tid & 15;   // pixel sub-tile (fast -> coalesced writes)
    const int to  = tid >> 4;   // oc sub-tile
    float acc[4][4] = {};
    for (int k0 = 0; k0 < C_; k0 += 16) {
        for (int e = tid; e < 1024; e += 256) {
            int k = e >> 6, p = e & 63;
            Vs[k][p] = kvd[((size_t)b * C2_ + C_ + k0 + k) * N_ + p0 + p];
            int oc = e >> 4, kk = e & 15;
            Ms[kk][oc] = Mm[((size_t)b * C_ + oc0 + oc) * C_ + k0 + kk];
        }
        __syncthreads();
        #pragma unroll
        for (int k = 0; k < 16; ++k) {
            float4 a = *(const float4*)&Vs[k][tp * 4];
            float4 w = *(const float4*)&Ms[k][to * 4];
            float av[4] = {a.x, a.y, a.z, a.w};
            float wv[4] = {w.x, w.y, w.z, w.w};
            #pragma unroll
            for (int i = 0; i < 4; ++i)
                #pragma unroll
                for (int j = 0; j < 4; ++j) acc[i][j] += wv[j] * av[i];
        }
        __syncthreads();
    }
    #pragma unroll
    for (int j = 0; j < 4; ++j) {
        const int oc = oc0 + to * 4 + j;
        float4 st = make_float4(acc[0][j], acc[1][j], acc[2][j], acc[3][j]);
        *(float4*)&out[((size_t)b * C_ + oc) * N_ + p0 + tp * 4] = st;
    }
}

extern "C" void kernel_launch(void* const* d_in, const int* in_sizes, int n_in,
                              void* d_out, int out_size, void* d_ws, size_t ws_size,
                              hipStream_t stream) {
    (void)in_sizes; (void)n_in; (void)out_size; (void)ws_size;
    const float* x     = (const float*)d_in[0];
    const float* q     = (const float*)d_in[1];
    const float* temp  = (const float*)d_in[2];
    const float* kvw   = (const float*)d_in[3];
    const float* offw  = (const float*)d_in[4];
    const float* offb  = (const float*)d_in[5];
    const float* regw  = (const float*)d_in[6];
    const float* projw = (const float*)d_in[7];

    float* out = (float*)d_out;                         // [B][C][N]
    float* qn  = out + (size_t)B_ * C_ * N_;            // [B][C][N] (output 1)
    // kvT scratch aliases the full d_out (50.33 MB, exactly B*N*C2 floats);
    // it is dead before qn/out are written.
    float* kvT = out;

    float* ws    = (float*)d_ws;
    float* kvd   = ws;                                   // B*C2*N
    float* offT  = kvd + (size_t)B_ * C2_ * N_;          // B*N*18
    float* regwT = offT + (size_t)B_ * N_ * 18;          // 9*C2*C2
    float* part  = regwT + (size_t)9 * C2_ * C2_;        // B*HEADS*NS*48*48
    float* attn  = part + (size_t)B_ * HEADS_ * NS_ * HD_ * HD_;
    float* knorm = attn + (size_t)B_ * HEADS_ * HD_ * HD_;
    float* Mm    = knorm + (size_t)B_ * C_;              // B*C*C

    k_regw_t<<<dim3((9 * C2_ * C2_ + 255) / 256), 256, 0, stream>>>(regw, regwT);
    k_kv1x1<<<dim3(N_ / 64, C2_ / 64, B_), 256, 0, stream>>>(x, kvw, kvT);
    k_offconv<<<dim3(N_ / 32, B_), 256, 0, stream>>>(kvT, offw, offb, offT);
    k_deform<<<dim3(N_ / 32, B_), 256, 0, stream>>>(kvT, offT, regwT, kvd);
    // kvT now dead; write outputs / attention path
    k_qnorm<<<dim3(B_ * C_), 256, 0, stream>>>(q, qn);
    k_knorm<<<dim3(B_ * C_), 256, 0, stream>>>(kvd, knorm);
    k_attn_partial<<<dim3(NS_, HEADS_, B_), 256, 0, stream>>>(qn, kvd, part);
    k_softmax<<<dim3(B_ * HEADS_ * HD_), 64, 0, stream>>>(part, knorm, temp, attn);
    k_m<<<dim3((B_ * C_ * C_ + 255) / 256), 256, 0, stream>>>(projw, attn, Mm);
    k_out<<<dim3(N_ / 64, C_ / 64, B_), 256, 0, stream>>>(Mm, kvd, out);
}

// Round 2
// 587.018 us; speedup vs baseline: 3.5280x; 3.5280x over previous
//
#include <hip/hip_runtime.h>
#include <math.h>

#define B_ 2
#define C_ 192
#define C2_ 384
#define H_ 128
#define W_ 128
#define N_ (H_*W_)      // 16384
#define HEADS_ 4
#define HD_ 48
#define NS_ 16
#define EPS_ 1e-12f

typedef __bf16 bf16x8 __attribute__((ext_vector_type(8)));
typedef float  f32x4  __attribute__((ext_vector_type(4)));

// ---------------- K0: pack reg_w [oc][c][t] -> regwP [t][c/32][oc][k] bf16 ----------------
__global__ __launch_bounds__(256) void k_regw_pack(const float* __restrict__ regw, ushort* __restrict__ regwP) {
    int idx = blockIdx.x * 256 + threadIdx.x;
    const int total = 9 * 12 * C2_ * 32;
    if (idx >= total) return;
    int t  = idx / (12 * C2_ * 32);
    int r  = idx - t * (12 * C2_ * 32);
    int ci = r / (C2_ * 32);
    int r2 = r - ci * (C2_ * 32);
    int oc = r2 >> 5;
    int kk = r2 & 31;
    int c  = ci * 32 + kk;
    float v = regw[(oc * C2_ + c) * 9 + t];
    union { __bf16 h; ushort u; } cv;
    cv.h = (__bf16)v;
    regwP[idx] = cv.u;
}

// ---------------- K1: kv 1x1 conv, output pixel-major kvT[b][p][oc] ----------------
__global__ __launch_bounds__(256) void k_kv1x1(const float* __restrict__ x, const float* __restrict__ kvw,
                                               float* __restrict__ kvT) {
    __shared__ float Xs[16][68];
    __shared__ float Ws[16][68];
    const int b   = blockIdx.z;
    const int p0  = blockIdx.x * 64;
    const int oc0 = blockIdx.y * 64;
    const int tid = threadIdx.x;
    const int tp  = tid >> 4;   // pixel sub-tile
    const int to  = tid & 15;   // oc sub-tile
    float acc[4][4] = {};
    for (int k0 = 0; k0 < C_; k0 += 16) {
        for (int e = tid; e < 1024; e += 256) {
            int k = e >> 6, p = e & 63;
            Xs[k][p] = x[((size_t)b * C_ + k0 + k) * N_ + p0 + p];
            int oc = e >> 4, kk = e & 15;
            Ws[kk][oc] = kvw[(oc0 + oc) * C_ + k0 + kk];
        }
        __syncthreads();
        #pragma unroll
        for (int k = 0; k < 16; ++k) {
            float4 a = *(const float4*)&Xs[k][tp * 4];
            float4 w = *(const float4*)&Ws[k][to * 4];
            float av[4] = {a.x, a.y, a.z, a.w};
            float wv[4] = {w.x, w.y, w.z, w.w};
            #pragma unroll
            for (int i = 0; i < 4; ++i)
                #pragma unroll
                for (int j = 0; j < 4; ++j) acc[i][j] += av[i] * wv[j];
        }
        __syncthreads();
    }
    #pragma unroll
    for (int i = 0; i < 4; ++i) {
        int p = p0 + tp * 4 + i;
        float4 st = make_float4(acc[i][0], acc[i][1], acc[i][2], acc[i][3]);
        *(float4*)&kvT[((size_t)b * N_ + p) * C2_ + oc0 + to * 4] = st;
    }
}

// ---------------- K2: normalize q rows over n, write to output qh region ----------------
__global__ __launch_bounds__(256) void k_qnorm(const float* __restrict__ q, float* __restrict__ qn) {
    const int row = blockIdx.x;       // b*C + c
    const float* src = q + (size_t)row * N_;
    float* dst = qn + (size_t)row * N_;
    float ss = 0.f;
    for (int i = threadIdx.x; i < N_ / 4; i += 256) {
        float4 v = ((const float4*)src)[i];
        ss += v.x * v.x + v.y * v.y + v.z * v.z + v.w * v.w;
    }
    __shared__ float red[256];
    red[threadIdx.x] = ss;
    __syncthreads();
    for (int s = 128; s > 0; s >>= 1) {
        if (threadIdx.x < s) red[threadIdx.x] += red[threadIdx.x + s];
        __syncthreads();
    }
    float rn = 1.f / fmaxf(sqrtf(red[0]), EPS_);
    for (int i = threadIdx.x; i < N_ / 4; i += 256) {
        float4 v = ((const float4*)src)[i];
        ((float4*)dst)[i] = make_float4(v.x * rn, v.y * rn, v.z * rn, v.w * rn);
    }
}

// ---------------- K5a: partial sum-of-squares of k rows (pixel-major kvdP) ----------------
__global__ __launch_bounds__(192) void k_knorm_part(const float* __restrict__ kvdP, float* __restrict__ knp) {
    const int b = blockIdx.y;
    const int chunk = blockIdx.x;      // 64 chunks of 256 pixels
    const int tid = threadIdx.x;       // 0..191 = k channel
    const float* base = kvdP + ((size_t)b * N_ + chunk * 256) * C2_ + tid;
    float ss = 0.f;
    for (int p = 0; p < 256; ++p) {
        float v = base[(size_t)p * C2_];
        ss += v * v;
    }
    knp[((size_t)b * 64 + chunk) * C_ + tid] = ss;
}

// ---------------- K3: offset conv3x3 (18 out ch), one wave per 8 pixels ----------------
__global__ __launch_bounds__(256) void k_offconv(const float* __restrict__ kvT, const float* __restrict__ offw,
                                                 const float* __restrict__ offb, float* __restrict__ offT) {
    const int b    = blockIdx.y;
    const int wv   = threadIdx.x >> 6;
    const int lane = threadIdx.x & 63;
    const int p0   = (blockIdx.x * 4 + wv) * 8;   // 8 consecutive pixels, same row
    const int y    = p0 >> 7;
    const int x0   = p0 & 127;
    const float* base = kvT + (size_t)b * N_ * C2_;
    #pragma unroll
    for (int half = 0; half < 2; ++half) {
        float acc[9][8];
        #pragma unroll
        for (int o = 0; o < 9; ++o)
            #pragma unroll
            for (int px = 0; px < 8; ++px) acc[o][px] = 0.f;
        for (int i = 0; i < 6; ++i) {
            const int c = i * 64 + lane;
            float vals[9][8];
            #pragma unroll
            for (int t = 0; t < 9; ++t) {
                const int dy = t / 3 - 1, dx = t % 3 - 1;
                const bool vy = (unsigned)(y + dy) < H_;
                #pragma unroll
                for (int px = 0; px < 8; ++px) {
                    const bool v = vy && ((unsigned)(x0 + px + dx) < W_);
                    const int qp = v ? (p0 + px + dy * W_ + dx) : 0;
                    float val = base[(size_t)qp * C2_ + c];
                    vals[t][px] = v ? val : 0.f;
                }
            }
            #pragma unroll
            for (int o = 0; o < 9; ++o) {
                const float* wp = offw + ((size_t)(half * 9 + o) * C2_ + c) * 9;
                float w9[9];
                #pragma unroll
                for (int t = 0; t < 9; ++t) w9[t] = wp[t];
                #pragma unroll
                for (int t = 0; t < 9; ++t)
                    #pragma unroll
                    for (int px = 0; px < 8; ++px) acc[o][px] += vals[t][px] * w9[t];
            }
        }
        #pragma unroll
        for (int o = 0; o < 9; ++o)
            #pragma unroll
            for (int px = 0; px < 8; ++px)
                #pragma unroll
                for (int m = 32; m > 0; m >>= 1)
                    acc[o][px] += __shfl_xor(acc[o][px], m);
        if (lane == 0) {
            #pragma unroll
            for (int px = 0; px < 8; ++px)
                #pragma unroll
                for (int o = 0; o < 9; ++o)
                    offT[((size_t)b * N_ + p0 + px) * 18 + half * 9 + o] = acc[o][px] + offb[half * 9 + o];
        }
    }
}

// ---------------- K4: deformable conv3x3 via bf16 MFMA -> kvdP[b][p][oc] pixel-major ----------------
__global__ __launch_bounds__(256) void k_deform_mfma(const float* __restrict__ kvT, const float* __restrict__ offT,
                                                     const __bf16* __restrict__ regwP, float* __restrict__ kvdP) {
    __shared__ __bf16 As[64 * 40];     // 64 px rows, 32 bf16 + 8 pad (2-way bank alias only)
    __shared__ __bf16 Ws[C2_ * 40];    // 384 oc rows, 32 bf16 + 8 pad
    __shared__ float  wwt[64][4];
    __shared__ int    widx[64][4];
    const int b    = blockIdx.y;
    const int p0   = blockIdx.x * 64;
    const int tid  = threadIdx.x;
    const int wv   = tid >> 6;          // wave 0..3 -> oc block of 96
    const int lane = tid & 63;
    const int fr   = lane & 15;         // fragment row/col index
    const int fg   = lane >> 4;         // fragment k-group / row-group
    const int spx  = tid >> 2;          // sampling: pixel 0..63
    const int ssub = (tid & 3) * 8;     // sampling: channel sub-offset
    const float* kb = kvT + (size_t)b * N_ * C2_;

    f32x4 acc[4][6];
    #pragma unroll
    for (int mg = 0; mg < 4; ++mg)
        #pragma unroll
        for (int ng = 0; ng < 6; ++ng) acc[mg][ng] = (f32x4){0.f, 0.f, 0.f, 0.f};

    for (int t = 0; t < 9; ++t) {
        if (tid < 64) {
            const int p = p0 + tid;
            const int yy = p >> 7, xx = p & 127;
            const float dy = offT[((size_t)b * N_ + p) * 18 + 2 * t];
            const float dx = offT[((size_t)b * N_ + p) * 18 + 2 * t + 1];
            const float py = (float)(yy + t / 3 - 1) + dy;
            const float px = (float)(xx + t % 3 - 1) + dx;
            const float fy = floorf(py), fx = floorf(px);
            const int y0 = (int)fy, x0i = (int)fx;
            const float ay = py - fy, ax = px - fx;
            #pragma unroll
            for (int j = 0; j < 4; ++j) {
                const int yi = y0 + (j >> 1);
                const int xi = x0i + (j & 1);
                const float wj = ((j >> 1) ? ay : 1.f - ay) * ((j & 1) ? ax : 1.f - ax);
                const bool v = ((unsigned)yi < H_) && ((unsigned)xi < W_);
                wwt[tid][j]  = v ? wj : 0.f;
                widx[tid][j] = v ? (yi * W_ + xi) : 0;
            }
        }
        __syncthreads();
        for (int ci = 0; ci < 12; ++ci) {
            const int cc = ci * 32;
            // ---- stage B: weights for (t, cc) chunk, [oc][k] padded rows ----
            const __bf16* wsrc = regwP + ((size_t)(t * 12 + ci) * C2_) * 32;
            #pragma unroll
            for (int i = 0; i < 6; ++i) {
                const int e = tid + i * 256;      // 0..1535
                const int oc = e >> 2, sg = e & 3;
                *(bf16x8*)&Ws[oc * 40 + sg * 8] = *(const bf16x8*)(wsrc + oc * 32 + sg * 8);
            }
            // ---- stage A: bilinear-sample 64 px x 32 ch -> bf16 ----
            {
                float s0 = 0.f, s1 = 0.f, s2 = 0.f, s3 = 0.f, s4 = 0.f, s5 = 0.f, s6 = 0.f, s7 = 0.f;
                const float* cb = kb + cc + ssub;
                #pragma unroll
                for (int j = 0; j < 4; ++j) {
                    const float w = wwt[spx][j];
                    const float* cp = cb + (size_t)widx[spx][j] * C2_;
                    float4 v0 = *(const float4*)cp;
                    float4 v1 = *(const float4*)(cp + 4);
                    s0 += w * v0.x; s1 += w * v0.y; s2 += w * v0.z; s3 += w * v0.w;
                    s4 += w * v1.x; s5 += w * v1.y; s6 += w * v1.z; s7 += w * v1.w;
                }
                bf16x8 pk = {(__bf16)s0, (__bf16)s1, (__bf16)s2, (__bf16)s3,
                             (__bf16)s4, (__bf16)s5, (__bf16)s6, (__bf16)s7};
                *(bf16x8*)&As[spx * 40 + ssub] = pk;
            }
            __syncthreads();
            // ---- MFMA: 4x6 fragments of 16x16, K=32 ----
            bf16x8 a[4];
            #pragma unroll
            for (int mg = 0; mg < 4; ++mg)
                a[mg] = *(const bf16x8*)&As[(mg * 16 + fr) * 40 + fg * 8];
            #pragma unroll
            for (int ng = 0; ng < 6; ++ng) {
                const bf16x8 bb = *(const bf16x8*)&Ws[(wv * 96 + ng * 16 + fr) * 40 + fg * 8];
                #pragma unroll
                for (int mg = 0; mg < 4; ++mg)
                    acc[mg][ng] = __builtin_amdgcn_mfma_f32_16x16x32_bf16(a[mg], bb, acc[mg][ng], 0, 0, 0);
            }
            __syncthreads();
        }
    }
    // ---- epilogue: C write, pixel-major (16 consecutive oc per 16-lane group) ----
    #pragma unroll
    for (int mg = 0; mg < 4; ++mg)
        #pragma unroll
        for (int j = 0; j < 4; ++j) {
            const int p = p0 + mg * 16 + fg * 4 + j;
            float* dst = kvdP + ((size_t)b * N_ + p) * C2_ + wv * 96 + fr;
            #pragma unroll
            for (int ng = 0; ng < 6; ++ng)
                dst[ng * 16] = acc[mg][ng][j];
        }
}

// ---------------- K6a: attention logits partial GEMM (48x48 per (b,h), split over n) ----------------
__global__ __launch_bounds__(256) void k_attn_partial(const float* __restrict__ qn, const float* __restrict__ kvdP,
                                                      float* __restrict__ part) {
    __shared__ float Qs[64][49];
    __shared__ float Ks[64][49];
    const int sl = blockIdx.x;
    const int h  = blockIdx.y;
    const int b  = blockIdx.z;
    const int tid = threadIdx.x;
    const int td = tid >> 4, te = tid & 15;
    const int n0 = sl * (N_ / NS_);
    float acc[3][3] = {};
    for (int nc = 0; nc < N_ / NS_; nc += 64) {
        for (int e = tid; e < HD_ * 64; e += 256) {
            int d = e >> 6, kk = e & 63;
            Qs[kk][d] = qn[((size_t)b * C_ + h * HD_ + d) * N_ + n0 + nc + kk];
        }
        for (int e = tid; e < 64 * HD_; e += 256) {
            int kk = e / HD_, d = e - kk * HD_;
            Ks[kk][d] = kvdP[((size_t)b * N_ + n0 + nc + kk) * C2_ + h * HD_ + d];
        }
        __syncthreads();
        #pragma unroll 8
        for (int kk = 0; kk < 64; ++kk) {
            float a[3], bb[3];
            #pragma unroll
            for (int i = 0; i < 3; ++i) a[i] = Qs[kk][td * 3 + i];
            #pragma unroll
            for (int j = 0; j < 3; ++j) bb[j] = Ks[kk][te * 3 + j];
            #pragma unroll
            for (int i = 0; i < 3; ++i)
                #pragma unroll
                for (int j = 0; j < 3; ++j) acc[i][j] += a[i] * bb[j];
        }
        __syncthreads();
    }
    float* pp = part + ((((size_t)b * HEADS_ + h) * NS_ + sl) * HD_) * HD_;
    #pragma unroll
    for (int i = 0; i < 3; ++i)
        #pragma unroll
        for (int j = 0; j < 3; ++j)
            pp[(td * 3 + i) * HD_ + te * 3 + j] = acc[i][j];
}

// ---------------- K6b: reduce partials, scale by 1/||k|| & temperature, softmax over e ----------------
__global__ __launch_bounds__(64) void k_softmax(const float* __restrict__ part, const float* __restrict__ knp,
                                                const float* __restrict__ temp, float* __restrict__ attn) {
    const int row = blockIdx.x;    // b*HEADS*HD + h*HD + d
    const int b = row / (HEADS_ * HD_);
    const int r = row % (HEADS_ * HD_);
    const int h = r / HD_;
    const int d = r % HD_;
    const int e = threadIdx.x;
    float v = -INFINITY;
    if (e < HD_) {
        float s = 0.f;
        for (int sl = 0; sl < NS_; ++sl)
            s += part[((((size_t)b * HEADS_ + h) * NS_ + sl) * HD_ + d) * HD_ + e];
        float sk = 0.f;
        for (int blk = 0; blk < 64; ++blk)
            sk += knp[((size_t)b * 64 + blk) * C_ + h * HD_ + e];
        v = s * (1.f / fmaxf(sqrtf(sk), EPS_)) * temp[h];
    }
    float m = v;
    #pragma unroll
    for (int off = 32; off > 0; off >>= 1) m = fmaxf(m, __shfl_xor(m, off));
    float ex = (e < HD_) ? expf(v - m) : 0.f;
    float sum = ex;
    #pragma unroll
    for (int off = 32; off > 0; off >>= 1) sum += __shfl_xor(sum, off);
    if (e < HD_)
        attn[(((size_t)b * HEADS_ + h) * HD_ + d) * HD_ + e] = ex / sum;
}

// ---------------- K7: fuse proj_w with attn: M[b][oc][h*48+e] ----------------
__global__ __launch_bounds__(256) void k_m(const float* __restrict__ projw, const float* __restrict__ attn,
                                           float* __restrict__ Mm) {
    const int gid = blockIdx.x * 256 + threadIdx.x;
    if (gid >= B_ * C_ * C_) return;
    const int b  = gid / (C_ * C_);
    const int r  = gid % (C_ * C_);
    const int oc = r / C_;
    const int he = r % C_;
    const int h = he / HD_;
    const int e = he % HD_;
    float s = 0.f;
    #pragma unroll 8
    for (int d = 0; d < HD_; ++d)
        s += projw[oc * C_ + h * HD_ + d] * attn[(((size_t)b * HEADS_ + h) * HD_ + d) * HD_ + e];
    Mm[gid] = s;
}

// ---------------- K8: out[b][oc][p] = sum_he M[b][oc][he] * v[b][p][he] (pixel-major V) ----------------
__global__ __launch_bounds__(256) void k_out(const float* __restrict__ Mm, const float* __restrict__ kvdP,
                                             float* __restrict__ out) {
    __shared__ float Vs[16][68];
    __shared__ float Ms[16][68];
    const int b   = blockIdx.z;
    const int p0  = blockIdx.x * 64;
    const int oc0 = blockIdx.y * 64;
    const int tid = threadIdx.x;
    const int tp  = tid & 15;   // pixel sub-tile (fast -> coalesced writes)
    const int to  = tid >> 4;   // oc sub-tile
    float acc[4][4] = {};
    for (int k0 = 0; k0 < C_; k0 += 16) {
        // V tile: read pixel-major rows (k contiguous), transpose into Vs[k][p]
        {
            const int p = tid >> 2, ks = (tid & 3) * 4;
            const float4 v = *(const float4*)&kvdP[((size_t)b * N_ + p0 + p) * C2_ + C_ + k0 + ks];
            Vs[ks + 0][p] = v.x; Vs[ks + 1][p] = v.y; Vs[ks + 2][p] = v.z; Vs[ks + 3][p] = v.w;
        }
        for (int e = tid; e < 1024; e += 256) {
            int oc = e >> 4, kk = e & 15;
            Ms[kk][oc] = Mm[((size_t)b * C_ + oc0 + oc) * C_ + k0 + kk];
        }
        __syncthreads();
        #pragma unroll
        for (int k = 0; k < 16; ++k) {
            float4 a = *(const float4*)&Vs[k][tp * 4];
            float4 w = *(const float4*)&Ms[k][to * 4];
            float av[4] = {a.x, a.y, a.z, a.w};
            float wv[4] = {w.x, w.y, w.z, w.w};
            #pragma unroll
            for (int i = 0; i < 4; ++i)
                #pragma unroll
                for (int j = 0; j < 4; ++j) acc[i][j] += wv[j] * av[i];
        }
        __syncthreads();
    }
    #pragma unroll
    for (int j = 0; j < 4; ++j) {
        const int oc = oc0 + to * 4 + j;
        float4 st = make_float4(acc[0][j], acc[1][j], acc[2][j], acc[3][j]);
        *(float4*)&out[((size_t)b * C_ + oc) * N_ + p0 + tp * 4] = st;
    }
}

extern "C" void kernel_launch(void* const* d_in, const int* in_sizes, int n_in,
                              void* d_out, int out_size, void* d_ws, size_t ws_size,
                              hipStream_t stream) {
    (void)in_sizes; (void)n_in; (void)out_size; (void)ws_size;
    const float* x     = (const float*)d_in[0];
    const float* q     = (const float*)d_in[1];
    const float* temp  = (const float*)d_in[2];
    const float* kvw   = (const float*)d_in[3];
    const float* offw  = (const float*)d_in[4];
    const float* offb  = (const float*)d_in[5];
    const float* regw  = (const float*)d_in[6];
    const float* projw = (const float*)d_in[7];

    float* out = (float*)d_out;                         // [B][C][N]
    float* qn  = out + (size_t)B_ * C_ * N_;            // [B][C][N] (output 1)
    // kvT scratch aliases the full d_out (50.33 MB); dead before qn/out are written.
    float* kvT = out;

    float*  ws    = (float*)d_ws;
    float*  kvdP  = ws;                                   // B*N*C2 (pixel-major)
    float*  offT  = kvdP + (size_t)B_ * N_ * C2_;         // B*N*18
    ushort* regwP = (ushort*)(offT + (size_t)B_ * N_ * 18); // 9*12*384*32 bf16
    float*  part  = (float*)regwP + (size_t)9 * 12 * C2_ * 32 / 2; // = + 663552 floats
    float*  attn  = part + (size_t)B_ * HEADS_ * NS_ * HD_ * HD_;
    float*  knp   = attn + (size_t)B_ * HEADS_ * HD_ * HD_;   // B*64*C
    float*  Mm    = knp + (size_t)B_ * 64 * C_;               // B*C*C

    k_regw_pack<<<dim3((9 * 12 * C2_ * 32 + 255) / 256), 256, 0, stream>>>(regw, regwP);
    k_kv1x1<<<dim3(N_ / 64, C2_ / 64, B_), 256, 0, stream>>>(x, kvw, kvT);
    k_offconv<<<dim3(N_ / 32, B_), 256, 0, stream>>>(kvT, offw, offb, offT);
    k_deform_mfma<<<dim3(N_ / 64, B_), 256, 0, stream>>>(kvT, offT, (const __bf16*)regwP, kvdP);
    // kvT now dead; write outputs / attention path
    k_qnorm<<<dim3(B_ * C_), 256, 0, stream>>>(q, qn);
    k_knorm_part<<<dim3(64, B_), 192, 0, stream>>>(kvdP, knp);
    k_attn_partial<<<dim3(NS_, HEADS_, B_), 256, 0, stream>>>(qn, kvdP, part);
    k_softmax<<<dim3(B_ * HEADS_ * HD_), 64, 0, stream>>>(part, knp, temp, attn);
    k_m<<<dim3((B_ * C_ * C_ + 255) / 256), 256, 0, stream>>>(projw, attn, Mm);
    k_out<<<dim3(N_ / 64, C_ / 64, B_), 256, 0, stream>>>(Mm, kvdP, out);
}